// Round 6
// baseline (438.972 us; speedup 1.0000x reference)
//
#include <hip/hip_runtime.h>

using u16 = unsigned short;
using u64 = unsigned long long;

// Problem constants (fixed by reference)
constexpr int BATCH = 64, SEQ = 1024, FEAT = 512, NBINS = 32;
constexpr int N = BATCH * SEQ;              // 65536 samples
constexpr int TAB = 131072;                 // hash table slots (2N), pow2
constexpr unsigned TABMASK = TAB - 1;
constexpr u64 EMPTY = ~0ull;                // combined <= 2^32-1, safe sentinel
constexpr double FXSCALE = 67108864.0;      // 2^26 fixed-point for stat atomics

// NOTE (R4 post-mortem): JAX reference under default config runs int64 as
// int32; left_shift(env, 32) on int32 is 0 in XLA, so the reference's
// combined id is the 32-bit key ONLY (env dropped). Verified R5: absmax 0.0.

// Workspace layout (bytes), total 2699648 (< 2760960 used in passing R5)
constexpr size_t OFF_KEYS = 0;              // u64[TAB]   1048576 (memset 0xFF)
constexpr size_t OFF_HEAD = 1048576;        // i32[TAB]   524288  (memset 0xFF -> -1)
constexpr size_t OFF_CNT = 1572864;         // u32[TAB]   524288  (memset 0x00)
constexpr size_t OFF_ISUMS = 2097152;       // i64[512]   4096    (memset 0x00)
constexpr size_t OFF_ISUMSQ = 2101248;      // i64[512]   4096    (memset 0x00)
constexpr size_t OFF_INVD = 2105344;        // f64[512]   4096    (1/sigma, f64)
constexpr size_t OFF_CD = 2109440;          // f64[32]    256
constexpr size_t OFF_QF = 2109696;          // f32[16384] 65536   (Q = P/sigma, f32)
constexpr size_t OFF_CF = 2175232;          // f32[32]    128
constexpr size_t OFF_SLOT = 2175360;        // i32[N]     262144
constexpr size_t OFF_NEXT = 2437504;        // i32[N]     262144

// ---------------- Kernel A: per-column sum / sumsq of f32 input
// fp64 regs, deterministic int fixed-point atomics. Loads batched 8-wide so
// 8 global_load_dwordx4 are in flight before first use (R5: VGPR=16 ->
// serialized loads -> latency-bound at 0.9 TB/s).
__global__ __launch_bounds__(256) void colstats_kernel(
    const float4* __restrict__ xv,  // f32 features, 8388608 float4s
    u64* __restrict__ isums, u64* __restrict__ isumsq) {
  const int t = threadIdx.x;
  const int gid = blockIdx.x * 256 + t;  // 512 blocks * 256 = 131072 threads
  double s0 = 0, s1 = 0, s2 = 0, s3 = 0, q0 = 0, q1 = 0, q2 = 0, q3 = 0;
  for (int kk = 0; kk < 64; kk += 8) {
    float4 v[8];
#pragma unroll
    for (int u = 0; u < 8; u++) v[u] = xv[gid + (kk + u) * 131072];
#pragma unroll
    for (int u = 0; u < 8; u++) {
      double a = (double)v[u].x, b = (double)v[u].y;
      double c = (double)v[u].z, d = (double)v[u].w;
      s0 += a; s1 += b; s2 += c; s3 += d;
      q0 += a * a; q1 += b * b; q2 += c * c; q3 += d * d;
    }
  }
  __shared__ double red[256 * 8];
  red[t * 8 + 0] = s0; red[t * 8 + 1] = s1; red[t * 8 + 2] = s2; red[t * 8 + 3] = s3;
  red[t * 8 + 4] = q0; red[t * 8 + 5] = q1; red[t * 8 + 6] = q2; red[t * 8 + 7] = q3;
  __syncthreads();
  if (t < 128) {
    // threads t and t+128 own the same 4 columns (gid mod 128 == t mod 128)
    double v[8];
#pragma unroll
    for (int u = 0; u < 8; u++) v[u] = red[t * 8 + u] + red[(t + 128) * 8 + u];
    const int c0 = 4 * t;
#pragma unroll
    for (int u = 0; u < 4; u++) {
      long long a = (long long)llrint(v[u] * FXSCALE);
      long long b = (long long)llrint(v[4 + u] * FXSCALE);
      atomicAdd(&isums[c0 + u], (u64)a);
      atomicAdd(&isumsq[c0 + u], (u64)b);
    }
  }
}

// ---------------- Kernel B: finalize mean/inv-sigma (f64). Emits:
//  invd f64[512], Qf f32[512][32] = P*inv, cd f64[32], cf f32[32].
// Deterministic reduction order throughout.
__global__ __launch_bounds__(512) void finalize_kernel(
    const float* __restrict__ P,  // f32 [512][32]
    const u64* __restrict__ isums, const u64* __restrict__ isumsq,
    double* __restrict__ invd, float* __restrict__ Qf,
    double* __restrict__ cd, float* __restrict__ cf) {
  __shared__ double meanArr[FEAT];
  __shared__ double invArr[FEAT];
  __shared__ double part[16][NBINS];
  const int t = threadIdx.x;  // t = feature index, 512 threads
  const double Nd = (double)N;
  const double tot = 1e-4 + Nd;
  double s = (double)(long long)isums[t] * (1.0 / FXSCALE);
  double ss = (double)(long long)isumsq[t] * (1.0 / FXSCALE);
  double bm = s / Nd;
  double bv = (ss - s * s / Nd) / (Nd - 1.0);  // unbiased var
  double mean = bm * Nd / tot;
  double M2 = 1e-4 + bv * Nd + bm * bm * 1e-4 * Nd / tot;
  double var = M2 / tot;
  double inv = 1.0 / sqrt(var + 1e-8);
  meanArr[t] = mean;
  invArr[t] = inv;
  invd[t] = inv;
#pragma unroll
  for (int j = 0; j < NBINS; j++) {
    Qf[t * NBINS + j] = (float)((double)P[t * NBINS + j] * inv);
  }
  __syncthreads();
  // c reduction: thread t handles bin j=t&31, feature block g=t>>5 (32 feats)
  {
    const int j = t & 31, g = t >> 5;
    double p = 0.0;
    for (int f = g * 32; f < g * 32 + 32; f++) {
      double qd = (double)P[f * NBINS + j] * invArr[f];
      p += meanArr[f] * qd;
    }
    part[g][j] = p;
  }
  __syncthreads();
  if (t < NBINS) {
    double c = 0.0;
    for (int g = 0; g < 16; g++) c += part[g][t];  // fixed order -> deterministic
    cd[t] = c;
    cf[t] = (float)c;
  }
}

// ---------------- Kernel C: per-sample key bits + hash insert.
// f32 main path; any bin with |acc - c| < TAU is recomputed in f64
// (gamma_512 * sum|x*q| ~= 4e-4 << TAU, so f32/f64 decisions provably agree
// outside the recheck band; inside it, f64 decides — identical to R5).
constexpr float TAU = 5e-3f;
__global__ __launch_bounds__(256) void project_kernel(
    const float4* __restrict__ xv, const float* __restrict__ feat,
    const float* __restrict__ P,
    const float* __restrict__ Qf, const float* __restrict__ cf,
    const double* __restrict__ invd, const double* __restrict__ cd,
    u64* __restrict__ keys_tab, int* __restrict__ head,
    unsigned* __restrict__ cnt, int* __restrict__ slot, int* __restrict__ nxt) {
  __shared__ __align__(16) float xt[64 * 132];  // 64 rows x 128 floats, stride 132
  __shared__ unsigned keyParts[64];
  const int t = threadIdx.x;
  const int rowBase = blockIdx.x * 64;
  const int lane = t & 63;
  const int wid = t >> 6;
  const int j0 = __builtin_amdgcn_readfirstlane(wid * 8);  // uniform -> scalar Qf loads
  if (t < 64) keyParts[t] = 0u;

  float acc[8] = {0, 0, 0, 0, 0, 0, 0, 0};
  for (int ch = 0; ch < 4; ch++) {  // feature chunks of 128
    __syncthreads();                // protects keyParts init / xt reuse
#pragma unroll
    for (int k = 0; k < 8; k++) {   // stage 64 rows x 32 float4
      int vi = t + k * 256;
      int r = vi >> 5, fv = vi & 31;
      float4 v = xv[(size_t)(rowBase + r) * 128 + ch * 32 + fv];
      *((float4*)&xt[r * 132 + fv * 4]) = v;
    }
    __syncthreads();
    const float* qbase = Qf + ch * 128 * NBINS + j0;
    const float4* xrow = (const float4*)&xt[lane * 132];
#pragma unroll 4
    for (int g = 0; g < 32; g++) {
      float4 x4 = xrow[g];
      const float* qp = qbase + g * 4 * NBINS;
#pragma unroll
      for (int j = 0; j < 8; j++) {
        float a = acc[j];
        a = fmaf(x4.x, qp[j], a);
        a = fmaf(x4.y, qp[NBINS + j], a);
        a = fmaf(x4.z, qp[2 * NBINS + j], a);
        a = fmaf(x4.w, qp[3 * NBINS + j], a);
        acc[j] = a;
      }
    }
  }
  unsigned part = 0;
  const float* xr = feat + (size_t)(rowBase + lane) * FEAT;
#pragma unroll
  for (int j = 0; j < 8; j++) {
    float m = acc[j] - cf[j0 + j];
    bool bit;
    if (__builtin_expect(fabsf(m) < TAU, 0)) {
      // f64 recheck: q_fj = (double)P * invd (one rounding), then fma chain.
      double da = 0.0;
      for (int f = 0; f < FEAT; f++) {
        double q = (double)P[f * NBINS + j0 + j] * invd[f];
        da = fma((double)xr[f], q, da);
      }
      bit = da > cd[j0 + j];
    } else {
      bit = m > 0.0f;
    }
    if (bit) part |= (1u << (j0 + j));
  }
  atomicOr(&keyParts[lane], part);
  __syncthreads();
  if (t < 64) {
    const int i = rowBase + t;
    unsigned key = keyParts[t];
    u64 combined = (u64)key;  // JAX int32 semantics: env<<32 vanished
    unsigned idx = (unsigned)((combined * 0x9E3779B97F4A7C15ull) >> 47) & TABMASK;
    for (;;) {
      u64 prev = atomicCAS(&keys_tab[idx], EMPTY, combined);
      if (prev == EMPTY || prev == combined) break;
      idx = (idx + 1) & TABMASK;
    }
    slot[i] = (int)idx;
    atomicAdd(&cnt[idx], 1u);
    nxt[i] = atomicExch(&head[idx], i);
  }
}

// ---------------- Kernel D: occurrence rank -> reward (order-independent)
__global__ __launch_bounds__(256) void count_kernel(
    const int* __restrict__ slot, const int* __restrict__ nxt,
    const int* __restrict__ head, const unsigned* __restrict__ cnt,
    float* __restrict__ out) {
  const int i = blockIdx.x * 256 + threadIdx.x;
  const int sl = slot[i];
  const unsigned c = cnt[sl];
  float r = 1.0f;
  if (c > 1u) {
    int j = head[sl];
    int occ = 1;
    while (j >= 0) {
      occ += (j < i) ? 1 : 0;
      j = nxt[j];
    }
    r = 1.0f / sqrtf((float)occ);
  }
  out[i] = r;
}

extern "C" void kernel_launch(void* const* d_in, const int* in_sizes, int n_in,
                              void* d_out, int out_size, void* d_ws, size_t ws_size,
                              hipStream_t stream) {
  const float4* xv = (const float4*)d_in[0];  // features f32 [64*1024][512]
  const float* feat = (const float*)d_in[0];
  const float* proj = (const float*)d_in[1];  // random_projection f32 [512][32]
  float* out = (float*)d_out;                 // [65536] f32
  char* ws = (char*)d_ws;

  u64* keys_tab = (u64*)(ws + OFF_KEYS);
  int* head = (int*)(ws + OFF_HEAD);
  unsigned* cnt = (unsigned*)(ws + OFF_CNT);
  u64* isums = (u64*)(ws + OFF_ISUMS);
  u64* isumsq = (u64*)(ws + OFF_ISUMSQ);
  double* invd = (double*)(ws + OFF_INVD);
  double* cd = (double*)(ws + OFF_CD);
  float* Qf = (float*)(ws + OFF_QF);
  float* cf = (float*)(ws + OFF_CF);
  int* slot = (int*)(ws + OFF_SLOT);
  int* nxt = (int*)(ws + OFF_NEXT);

  // init: keys_tab + head -> 0xFF (EMPTY / -1); cnt + isums + isumsq -> 0
  hipMemsetAsync(ws + OFF_KEYS, 0xFF, OFF_CNT - OFF_KEYS, stream);
  hipMemsetAsync(ws + OFF_CNT, 0x00, OFF_INVD - OFF_CNT, stream);

  colstats_kernel<<<512, 256, 0, stream>>>(xv, isums, isumsq);
  finalize_kernel<<<1, 512, 0, stream>>>(proj, isums, isumsq, invd, Qf, cd, cf);
  project_kernel<<<N / 64, 256, 0, stream>>>(xv, feat, proj, Qf, cf, invd, cd,
                                             keys_tab, head, cnt, slot, nxt);
  count_kernel<<<N / 256, 256, 0, stream>>>(slot, nxt, head, cnt, out);
}

// Round 7
// 337.017 us; speedup vs baseline: 1.3025x; 1.3025x over previous
//
#include <hip/hip_runtime.h>

using u16 = unsigned short;
using u64 = unsigned long long;

// Problem constants (fixed by reference)
constexpr int BATCH = 64, SEQ = 1024, FEAT = 512, NBINS = 32;
constexpr int N = BATCH * SEQ;              // 65536 samples
constexpr int TAB = 131072;                 // hash table slots (2N), pow2
constexpr unsigned TABMASK = TAB - 1;
constexpr u64 EMPTY = ~0ull;                // combined <= 2^32-1, safe sentinel
constexpr double FXSCALE = 67108864.0;      // 2^26 fixed-point for stat atomics

// NOTE (R4): JAX reference under default config runs int64 as int32;
// left_shift(env, 32) on int32 is 0 in XLA -> combined id is the 32-bit key
// ONLY (env dropped). Verified R5/R6: absmax 0.0.

// Workspace layout (bytes), total 2826624
constexpr size_t OFF_KEYS = 0;              // u64[TAB]   1048576 (memset 0xFF)
constexpr size_t OFF_HEAD = 1048576;        // i32[TAB]   524288  (memset 0xFF -> -1)
constexpr size_t OFF_CNT = 1572864;         // u32[TAB]   524288  (memset 0x00)
constexpr size_t OFF_ISUMS = 2097152;       // i64[512]   4096    (memset 0x00)
constexpr size_t OFF_ISUMSQ = 2101248;      // i64[512]   4096    (memset 0x00)
constexpr size_t OFF_QD = 2105344;          // f64[16384] 131072  (Q = P/sigma, f64)
constexpr size_t OFF_CD = 2236416;          // f64[32]    256
constexpr size_t OFF_QF = 2236672;          // f32[16384] 65536   (Q = P/sigma, f32)
constexpr size_t OFF_CF = 2302208;          // f32[32]    128
constexpr size_t OFF_SLOT = 2302336;        // i32[N]     262144
constexpr size_t OFF_NEXT = 2564480;        // i32[N]     262144

// ---------------- Kernel A: per-column sum / sumsq of f32 input.
// R6 post-mortem: 512 blocks = 2 blocks/CU was grid-limited (occupancy 16%,
// 0.9 TB/s, VALUBusy 3%). Now 1024 blocks x 32 vec/thread in 4 batches of 8
// explicit in-flight dwordx4 loads. Deterministic int fixed-point atomics.
__global__ __launch_bounds__(256) void colstats_kernel(
    const float4* __restrict__ xv,  // f32 features, 8388608 float4s
    u64* __restrict__ isums, u64* __restrict__ isumsq) {
  const int t = threadIdx.x;
  const int L = blockIdx.x * 256 + t;  // 1024 blocks * 256 = 262144 threads
  double s0 = 0, s1 = 0, s2 = 0, s3 = 0, q0 = 0, q1 = 0, q2 = 0, q3 = 0;
  for (int mm = 0; mm < 32; mm += 8) {
    float4 v[8];
#pragma unroll
    for (int u = 0; u < 8; u++) v[u] = xv[L + (mm + u) * 262144];
#pragma unroll
    for (int u = 0; u < 8; u++) {
      double a = (double)v[u].x, b = (double)v[u].y;
      double c = (double)v[u].z, d = (double)v[u].w;
      s0 += a; s1 += b; s2 += c; s3 += d;
      q0 += a * a; q1 += b * b; q2 += c * c; q3 += d * d;
    }
  }
  __shared__ double red[256 * 8];  // 16 KB
  red[t * 8 + 0] = s0; red[t * 8 + 1] = s1; red[t * 8 + 2] = s2; red[t * 8 + 3] = s3;
  red[t * 8 + 4] = q0; red[t * 8 + 5] = q1; red[t * 8 + 6] = q2; red[t * 8 + 7] = q3;
  __syncthreads();
  if (t < 128) {
    // threads t and t+128 own the same 4 columns (262144 % 128 == 0)
    double v[8];
#pragma unroll
    for (int u = 0; u < 8; u++) v[u] = red[t * 8 + u] + red[(t + 128) * 8 + u];
    const int c0 = 4 * t;
#pragma unroll
    for (int u = 0; u < 4; u++) {
      long long a = (long long)llrint(v[u] * FXSCALE);
      long long b = (long long)llrint(v[4 + u] * FXSCALE);
      atomicAdd(&isums[c0 + u], (u64)a);
      atomicAdd(&isumsq[c0 + u], (u64)b);
    }
  }
}

// ---------------- Kernel B: finalize mean/inv-sigma (f64). Emits Qd f64 (for
// recheck), Qf f32 (main path), cd f64, cf f32. Deterministic order.
__global__ __launch_bounds__(512) void finalize_kernel(
    const float* __restrict__ P,  // f32 [512][32]
    const u64* __restrict__ isums, const u64* __restrict__ isumsq,
    double* __restrict__ Qd, float* __restrict__ Qf,
    double* __restrict__ cd, float* __restrict__ cf) {
  __shared__ double meanArr[FEAT];
  __shared__ double invArr[FEAT];
  __shared__ double part[16][NBINS];
  const int t = threadIdx.x;  // t = feature index, 512 threads
  const double Nd = (double)N;
  const double tot = 1e-4 + Nd;
  double s = (double)(long long)isums[t] * (1.0 / FXSCALE);
  double ss = (double)(long long)isumsq[t] * (1.0 / FXSCALE);
  double bm = s / Nd;
  double bv = (ss - s * s / Nd) / (Nd - 1.0);  // unbiased var
  double mean = bm * Nd / tot;
  double M2 = 1e-4 + bv * Nd + bm * bm * 1e-4 * Nd / tot;
  double var = M2 / tot;
  double inv = 1.0 / sqrt(var + 1e-8);
  meanArr[t] = mean;
  invArr[t] = inv;
#pragma unroll
  for (int j = 0; j < NBINS; j++) {
    double qd = (double)P[t * NBINS + j] * inv;
    Qd[t * NBINS + j] = qd;
    Qf[t * NBINS + j] = (float)qd;
  }
  __syncthreads();
  // c reduction: thread t handles bin j=t&31, feature block g=t>>5 (32 feats)
  {
    const int j = t & 31, g = t >> 5;
    double p = 0.0;
    for (int f = g * 32; f < g * 32 + 32; f++) {
      double qd = (double)P[f * NBINS + j] * invArr[f];
      p += meanArr[f] * qd;
    }
    part[g][j] = p;
  }
  __syncthreads();
  if (t < NBINS) {
    double c = 0.0;
    for (int g = 0; g < 16; g++) c += part[g][t];  // fixed order -> deterministic
    cd[t] = c;
    cf[t] = (float)c;
  }
}

// ---------------- Kernel C: per-sample key bits + hash insert.
// f32 main path. Borderline bins (|margin| < TAU; f32 error bound ~4.3e-4)
// are re-decided by a WAVE-COOPERATIVE f64 dot (R6 post-mortem: per-lane
// serial 512-iter recheck cost 125 µs). ~0.8 rechecks/wave expected.
constexpr float TAU = 2.5e-3f;
__global__ __launch_bounds__(256) void project_kernel(
    const float4* __restrict__ xv, const float* __restrict__ feat,
    const float* __restrict__ Qf, const float* __restrict__ cf,
    const double* __restrict__ Qd, const double* __restrict__ cd,
    u64* __restrict__ keys_tab, int* __restrict__ head,
    unsigned* __restrict__ cnt, int* __restrict__ slot, int* __restrict__ nxt) {
  __shared__ __align__(16) float xt[64 * 132];  // 64 rows x 128 floats, stride 132
  __shared__ unsigned keyParts[64];
  const int t = threadIdx.x;
  const int rowBase = blockIdx.x * 64;
  const int lane = t & 63;
  const int wid = t >> 6;
  const int j0 = __builtin_amdgcn_readfirstlane(wid * 8);  // uniform -> scalar Qf loads
  if (t < 64) keyParts[t] = 0u;

  float acc[8] = {0, 0, 0, 0, 0, 0, 0, 0};
  for (int ch = 0; ch < 4; ch++) {  // feature chunks of 128
    __syncthreads();                // protects keyParts init / xt reuse
#pragma unroll
    for (int k = 0; k < 8; k++) {   // stage 64 rows x 32 float4
      int vi = t + k * 256;
      int r = vi >> 5, fv = vi & 31;
      float4 v = xv[(size_t)(rowBase + r) * 128 + ch * 32 + fv];
      *((float4*)&xt[r * 132 + fv * 4]) = v;
    }
    __syncthreads();
    const float* qbase = Qf + ch * 128 * NBINS + j0;
    const float4* xrow = (const float4*)&xt[lane * 132];
#pragma unroll 4
    for (int g = 0; g < 32; g++) {
      float4 x4 = xrow[g];
      const float* qp = qbase + g * 4 * NBINS;
#pragma unroll
      for (int j = 0; j < 8; j++) {
        float a = acc[j];
        a = fmaf(x4.x, qp[j], a);
        a = fmaf(x4.y, qp[NBINS + j], a);
        a = fmaf(x4.z, qp[2 * NBINS + j], a);
        a = fmaf(x4.w, qp[3 * NBINS + j], a);
        acc[j] = a;
      }
    }
  }
  // f32 decisions + margins
  unsigned part = 0;
  float m[8];
#pragma unroll
  for (int j = 0; j < 8; j++) {
    m[j] = acc[j] - cf[j0 + j];
    if (m[j] > 0.0f) part |= (1u << (j0 + j));
  }
  // wave-cooperative f64 recheck of borderline bins (uniform control flow)
  for (int j = 0; j < 8; j++) {
    u64 mask = __ballot(fabsf(m[j]) < TAU);
    const int jj = j0 + j;
    while (mask) {
      const int L = (int)__builtin_ctzll(mask);
      mask &= mask - 1;
      // all 64 lanes: lane handles feats lane*8..lane*8+7 of row rowBase+L
      const float* xr = feat + (size_t)(rowBase + L) * FEAT + lane * 8;
      const double* qp = Qd + (size_t)(lane * 8) * NBINS + jj;
      double p = 0.0;
#pragma unroll
      for (int u = 0; u < 8; u++)
        p = fma((double)xr[u], qp[u * NBINS], p);
      // fixed-order f64 butterfly allreduce across 64 lanes
#pragma unroll
      for (int off = 32; off > 0; off >>= 1) p += __shfl_xor(p, off, 64);
      const bool bit = p > cd[jj];
      if (lane == L) {
        if (bit) part |= (1u << jj);
        else part &= ~(1u << jj);
      }
    }
  }
  atomicOr(&keyParts[lane], part);
  __syncthreads();
  if (t < 64) {
    const int i = rowBase + t;
    unsigned key = keyParts[t];
    u64 combined = (u64)key;  // JAX int32 semantics: env<<32 vanished
    unsigned idx = (unsigned)((combined * 0x9E3779B97F4A7C15ull) >> 47) & TABMASK;
    for (;;) {
      u64 prev = atomicCAS(&keys_tab[idx], EMPTY, combined);
      if (prev == EMPTY || prev == combined) break;
      idx = (idx + 1) & TABMASK;
    }
    slot[i] = (int)idx;
    atomicAdd(&cnt[idx], 1u);
    nxt[i] = atomicExch(&head[idx], i);
  }
}

// ---------------- Kernel D: occurrence rank -> reward (order-independent)
__global__ __launch_bounds__(256) void count_kernel(
    const int* __restrict__ slot, const int* __restrict__ nxt,
    const int* __restrict__ head, const unsigned* __restrict__ cnt,
    float* __restrict__ out) {
  const int i = blockIdx.x * 256 + threadIdx.x;
  const int sl = slot[i];
  const unsigned c = cnt[sl];
  float r = 1.0f;
  if (c > 1u) {
    int j = head[sl];
    int occ = 1;
    while (j >= 0) {
      occ += (j < i) ? 1 : 0;
      j = nxt[j];
    }
    r = 1.0f / sqrtf((float)occ);
  }
  out[i] = r;
}

extern "C" void kernel_launch(void* const* d_in, const int* in_sizes, int n_in,
                              void* d_out, int out_size, void* d_ws, size_t ws_size,
                              hipStream_t stream) {
  const float4* xv = (const float4*)d_in[0];  // features f32 [64*1024][512]
  const float* feat = (const float*)d_in[0];
  const float* proj = (const float*)d_in[1];  // random_projection f32 [512][32]
  float* out = (float*)d_out;                 // [65536] f32
  char* ws = (char*)d_ws;

  u64* keys_tab = (u64*)(ws + OFF_KEYS);
  int* head = (int*)(ws + OFF_HEAD);
  unsigned* cnt = (unsigned*)(ws + OFF_CNT);
  u64* isums = (u64*)(ws + OFF_ISUMS);
  u64* isumsq = (u64*)(ws + OFF_ISUMSQ);
  double* Qd = (double*)(ws + OFF_QD);
  double* cd = (double*)(ws + OFF_CD);
  float* Qf = (float*)(ws + OFF_QF);
  float* cf = (float*)(ws + OFF_CF);
  int* slot = (int*)(ws + OFF_SLOT);
  int* nxt = (int*)(ws + OFF_NEXT);

  // init: keys_tab + head -> 0xFF (EMPTY / -1); cnt + isums + isumsq -> 0
  hipMemsetAsync(ws + OFF_KEYS, 0xFF, OFF_CNT - OFF_KEYS, stream);
  hipMemsetAsync(ws + OFF_CNT, 0x00, OFF_QD - OFF_CNT, stream);

  colstats_kernel<<<1024, 256, 0, stream>>>(xv, isums, isumsq);
  finalize_kernel<<<1, 512, 0, stream>>>(proj, isums, isumsq, Qd, Qf, cd, cf);
  project_kernel<<<N / 64, 256, 0, stream>>>(xv, feat, Qf, cf, Qd, cd,
                                             keys_tab, head, cnt, slot, nxt);
  count_kernel<<<N / 256, 256, 0, stream>>>(slot, nxt, head, cnt, out);
}

// Round 8
// 295.435 us; speedup vs baseline: 1.4858x; 1.1407x over previous
//
#include <hip/hip_runtime.h>

using u16 = unsigned short;
using u64 = unsigned long long;

// Problem constants (fixed by reference)
constexpr int BATCH = 64, SEQ = 1024, FEAT = 512, NBINS = 32;
constexpr int N = BATCH * SEQ;              // 65536 samples
constexpr int TAB = 131072;                 // hash table slots (2N), pow2
constexpr unsigned TABMASK = TAB - 1;
constexpr u64 EMPTY = ~0ull;                // combined <= 2^32-1, safe sentinel
constexpr double FXSCALE = 67108864.0;      // 2^26 fixed-point for stat atomics
constexpr int NSHADOW = 64;                 // shadow accumulators (R7: one array
                                            // -> 1024-deep serial atomic chains)

// NOTE (R4): JAX reference under default config runs int64 as int32;
// left_shift(env, 32) on int32 is 0 in XLA -> combined id is the 32-bit key
// ONLY (env dropped). Verified R5/R6/R7: absmax 0.0.

// Workspace layout (bytes), total 3347072
constexpr size_t OFF_KEYS = 0;              // u64[TAB]       1048576 (memset 0xFF)
constexpr size_t OFF_HEAD = 1048576;        // i32[TAB]       524288  (memset 0xFF -> -1)
constexpr size_t OFF_CNT = 1572864;         // u32[TAB]       524288  (memset 0x00)
constexpr size_t OFF_SHAD = 2097152;        // u64[64][1024]  524288  (memset 0x00)
                                            //   [s][c]      = fx sum  col c (c<512)
                                            //   [s][512+c]  = fx sumsq col c
constexpr size_t OFF_QD = 2621440;          // f64[16384]     131072  (Q = P/sigma, f64)
constexpr size_t OFF_CD = 2752512;          // f64[32]        256
constexpr size_t OFF_QF = 2752768;          // f32[16384]     65536   (Q = P/sigma, f32)
constexpr size_t OFF_CF = 2818304;          // f32[32]        128
constexpr size_t OFF_SLOT = 2818432;        // i32[N]         262144
constexpr size_t OFF_NEXT = 3080576;        // i32[N]         262144

// ---------------- Kernel A: per-column sum / sumsq of f32 input.
// f64 regs; deterministic int fixed-point atomics into 64 shadow arrays
// (chain depth 16 instead of 1024 — R7's 117 us was the serial atomic tail).
__global__ __launch_bounds__(256, 4) void colstats_kernel(
    const float4* __restrict__ xv,  // f32 features, 8388608 float4s
    u64* __restrict__ shad) {
  const int t = threadIdx.x;
  const int L = blockIdx.x * 256 + t;  // 1024 blocks * 256 = 262144 threads
  double s0 = 0, s1 = 0, s2 = 0, s3 = 0, q0 = 0, q1 = 0, q2 = 0, q3 = 0;
  for (int mm = 0; mm < 32; mm += 8) {
    float4 v[8];
#pragma unroll
    for (int u = 0; u < 8; u++) v[u] = xv[L + (mm + u) * 262144];
#pragma unroll
    for (int u = 0; u < 8; u++) {
      double a = (double)v[u].x, b = (double)v[u].y;
      double c = (double)v[u].z, d = (double)v[u].w;
      s0 += a; s1 += b; s2 += c; s3 += d;
      q0 += a * a; q1 += b * b; q2 += c * c; q3 += d * d;
    }
  }
  __shared__ double red[256 * 8];  // 16 KB
  red[t * 8 + 0] = s0; red[t * 8 + 1] = s1; red[t * 8 + 2] = s2; red[t * 8 + 3] = s3;
  red[t * 8 + 4] = q0; red[t * 8 + 5] = q1; red[t * 8 + 6] = q2; red[t * 8 + 7] = q3;
  __syncthreads();
  if (t < 128) {
    // threads t and t+128 own the same 4 columns (262144 % 128 == 0)
    double v[8];
#pragma unroll
    for (int u = 0; u < 8; u++) v[u] = red[t * 8 + u] + red[(t + 128) * 8 + u];
    const int c0 = 4 * t;
    u64* sh = shad + (size_t)(blockIdx.x & (NSHADOW - 1)) * 1024;
#pragma unroll
    for (int u = 0; u < 4; u++) {
      long long a = (long long)llrint(v[u] * FXSCALE);
      long long b = (long long)llrint(v[4 + u] * FXSCALE);
      atomicAdd(&sh[c0 + u], (u64)a);
      atomicAdd(&sh[512 + c0 + u], (u64)b);
    }
  }
}

// ---------------- Kernel B: merge shadows (fixed order), finalize mean/inv-sigma
// (f64), emit Qd f64 (recheck), Qf f32 (main), cd f64, cf f32. Deterministic.
__global__ __launch_bounds__(512) void finalize_kernel(
    const float* __restrict__ P,  // f32 [512][32]
    const u64* __restrict__ shad,
    double* __restrict__ Qd, float* __restrict__ Qf,
    double* __restrict__ cd, float* __restrict__ cf) {
  __shared__ double meanArr[FEAT];
  __shared__ double invArr[FEAT];
  __shared__ double part[16][NBINS];
  const int t = threadIdx.x;  // t = feature index, 512 threads
  long long isum = 0, isumsq = 0;
  for (int sh = 0; sh < NSHADOW; sh++) {  // fixed order (int adds: exact anyway)
    isum += (long long)shad[sh * 1024 + t];
    isumsq += (long long)shad[sh * 1024 + 512 + t];
  }
  const double Nd = (double)N;
  const double tot = 1e-4 + Nd;
  double s = (double)isum * (1.0 / FXSCALE);
  double ss = (double)isumsq * (1.0 / FXSCALE);
  double bm = s / Nd;
  double bv = (ss - s * s / Nd) / (Nd - 1.0);  // unbiased var
  double mean = bm * Nd / tot;
  double M2 = 1e-4 + bv * Nd + bm * bm * 1e-4 * Nd / tot;
  double var = M2 / tot;
  double inv = 1.0 / sqrt(var + 1e-8);
  meanArr[t] = mean;
  invArr[t] = inv;
#pragma unroll
  for (int j = 0; j < NBINS; j++) {
    double qd = (double)P[t * NBINS + j] * inv;
    Qd[t * NBINS + j] = qd;
    Qf[t * NBINS + j] = (float)qd;
  }
  __syncthreads();
  // c reduction: thread t handles bin j=t&31, feature block g=t>>5 (32 feats)
  {
    const int j = t & 31, g = t >> 5;
    double p = 0.0;
    for (int f = g * 32; f < g * 32 + 32; f++) {
      double qd = (double)P[f * NBINS + j] * invArr[f];
      p += meanArr[f] * qd;
    }
    part[g][j] = p;
  }
  __syncthreads();
  if (t < NBINS) {
    double c = 0.0;
    for (int g = 0; g < 16; g++) c += part[g][t];  // fixed order -> deterministic
    cd[t] = c;
    cf[t] = (float)c;
  }
}

// ---------------- Kernel C: per-sample key bits + hash insert.
// f32 main path with Qf staged in LDS (R7: ~4096 wave-uniform GLOBAL loads per
// wave were VMEM-latency-bound; uniform-address ds_read_b128 is broadcast,
// conflict-free). Borderline bins (|margin| < TAU; f32 bound ~4.3e-4) are
// re-decided by the wave-cooperative f64 dot (validated R7).
constexpr float TAU = 2.5e-3f;
__global__ __launch_bounds__(256) void project_kernel(
    const float4* __restrict__ xv, const float* __restrict__ feat,
    const float4* __restrict__ Qf4, const float* __restrict__ cf,
    const double* __restrict__ Qd, const double* __restrict__ cd,
    u64* __restrict__ keys_tab, int* __restrict__ head,
    unsigned* __restrict__ cnt, int* __restrict__ slot, int* __restrict__ nxt) {
  __shared__ __align__(16) float xt[64 * 132];   // 64 rows x 128 floats, stride 132
  __shared__ __align__(16) float qt[128 * 32];   // Qf chunk: 128 feats x 32 bins, 16 KB
  __shared__ unsigned keyParts[64];
  const int t = threadIdx.x;
  const int rowBase = blockIdx.x * 64;
  const int lane = t & 63;
  const int wid = t >> 6;
  const int j0 = __builtin_amdgcn_readfirstlane(wid * 8);
  if (t < 64) keyParts[t] = 0u;
  float4* qt4 = (float4*)qt;

  float acc[8] = {0, 0, 0, 0, 0, 0, 0, 0};
  for (int ch = 0; ch < 4; ch++) {  // feature chunks of 128
    __syncthreads();                // protects keyParts init / xt,qt reuse
#pragma unroll
    for (int k = 0; k < 8; k++) {   // stage 64 rows x 32 float4
      int vi = t + k * 256;
      int r = vi >> 5, fv = vi & 31;
      float4 v = xv[(size_t)(rowBase + r) * 128 + ch * 32 + fv];
      *((float4*)&xt[r * 132 + fv * 4]) = v;
    }
#pragma unroll
    for (int k = 0; k < 4; k++) {   // stage Qf chunk: 1024 float4
      int qi = t + k * 256;
      qt4[qi] = Qf4[ch * 1024 + qi];
    }
    __syncthreads();
    const float4* xrow = (const float4*)&xt[lane * 132];
#pragma unroll 4
    for (int g = 0; g < 32; g++) {
      float4 x4 = xrow[g];
      float xs[4] = {x4.x, x4.y, x4.z, x4.w};
#pragma unroll
      for (int ff = 0; ff < 4; ff++) {
        const int fl = 4 * g + ff;
        float4 qlo = qt4[(fl * 32 + j0) >> 2];       // uniform addr -> broadcast
        float4 qhi = qt4[(fl * 32 + j0 + 4) >> 2];
        float x = xs[ff];
        acc[0] = fmaf(x, qlo.x, acc[0]);
        acc[1] = fmaf(x, qlo.y, acc[1]);
        acc[2] = fmaf(x, qlo.z, acc[2]);
        acc[3] = fmaf(x, qlo.w, acc[3]);
        acc[4] = fmaf(x, qhi.x, acc[4]);
        acc[5] = fmaf(x, qhi.y, acc[5]);
        acc[6] = fmaf(x, qhi.z, acc[6]);
        acc[7] = fmaf(x, qhi.w, acc[7]);
      }
    }
  }
  // f32 decisions + margins
  unsigned part = 0;
  float m[8];
#pragma unroll
  for (int j = 0; j < 8; j++) {
    m[j] = acc[j] - cf[j0 + j];
    if (m[j] > 0.0f) part |= (1u << (j0 + j));
  }
  // wave-cooperative f64 recheck of borderline bins (uniform control flow)
  for (int j = 0; j < 8; j++) {
    u64 mask = __ballot(fabsf(m[j]) < TAU);
    const int jj = j0 + j;
    while (mask) {
      const int L = (int)__builtin_ctzll(mask);
      mask &= mask - 1;
      // all 64 lanes: lane handles feats lane*8..lane*8+7 of row rowBase+L
      const float* xr = feat + (size_t)(rowBase + L) * FEAT + lane * 8;
      const double* qp = Qd + (size_t)(lane * 8) * NBINS + jj;
      double p = 0.0;
#pragma unroll
      for (int u = 0; u < 8; u++)
        p = fma((double)xr[u], qp[u * NBINS], p);
      // fixed-order f64 butterfly allreduce across 64 lanes
#pragma unroll
      for (int off = 32; off > 0; off >>= 1) p += __shfl_xor(p, off, 64);
      const bool bit = p > cd[jj];
      if (lane == L) {
        if (bit) part |= (1u << jj);
        else part &= ~(1u << jj);
      }
    }
  }
  atomicOr(&keyParts[lane], part);
  __syncthreads();
  if (t < 64) {
    const int i = rowBase + t;
    unsigned key = keyParts[t];
    u64 combined = (u64)key;  // JAX int32 semantics: env<<32 vanished
    unsigned idx = (unsigned)((combined * 0x9E3779B97F4A7C15ull) >> 47) & TABMASK;
    for (;;) {
      u64 prev = atomicCAS(&keys_tab[idx], EMPTY, combined);
      if (prev == EMPTY || prev == combined) break;
      idx = (idx + 1) & TABMASK;
    }
    slot[i] = (int)idx;
    atomicAdd(&cnt[idx], 1u);
    nxt[i] = atomicExch(&head[idx], i);
  }
}

// ---------------- Kernel D: occurrence rank -> reward (order-independent)
__global__ __launch_bounds__(256) void count_kernel(
    const int* __restrict__ slot, const int* __restrict__ nxt,
    const int* __restrict__ head, const unsigned* __restrict__ cnt,
    float* __restrict__ out) {
  const int i = blockIdx.x * 256 + threadIdx.x;
  const int sl = slot[i];
  const unsigned c = cnt[sl];
  float r = 1.0f;
  if (c > 1u) {
    int j = head[sl];
    int occ = 1;
    while (j >= 0) {
      occ += (j < i) ? 1 : 0;
      j = nxt[j];
    }
    r = 1.0f / sqrtf((float)occ);
  }
  out[i] = r;
}

extern "C" void kernel_launch(void* const* d_in, const int* in_sizes, int n_in,
                              void* d_out, int out_size, void* d_ws, size_t ws_size,
                              hipStream_t stream) {
  const float4* xv = (const float4*)d_in[0];  // features f32 [64*1024][512]
  const float* feat = (const float*)d_in[0];
  const float* proj = (const float*)d_in[1];  // random_projection f32 [512][32]
  float* out = (float*)d_out;                 // [65536] f32
  char* ws = (char*)d_ws;

  u64* keys_tab = (u64*)(ws + OFF_KEYS);
  int* head = (int*)(ws + OFF_HEAD);
  unsigned* cnt = (unsigned*)(ws + OFF_CNT);
  u64* shad = (u64*)(ws + OFF_SHAD);
  double* Qd = (double*)(ws + OFF_QD);
  double* cd = (double*)(ws + OFF_CD);
  float* Qf = (float*)(ws + OFF_QF);
  float* cf = (float*)(ws + OFF_CF);
  int* slot = (int*)(ws + OFF_SLOT);
  int* nxt = (int*)(ws + OFF_NEXT);

  // init: keys_tab + head -> 0xFF (EMPTY / -1); cnt + shadows -> 0
  hipMemsetAsync(ws + OFF_KEYS, 0xFF, OFF_CNT - OFF_KEYS, stream);
  hipMemsetAsync(ws + OFF_CNT, 0x00, OFF_QD - OFF_CNT, stream);

  colstats_kernel<<<1024, 256, 0, stream>>>(xv, shad);
  finalize_kernel<<<1, 512, 0, stream>>>(proj, shad, Qd, Qf, cd, cf);
  project_kernel<<<N / 64, 256, 0, stream>>>(xv, feat, (const float4*)Qf, cf, Qd, cd,
                                             keys_tab, head, cnt, slot, nxt);
  count_kernel<<<N / 256, 256, 0, stream>>>(slot, nxt, head, cnt, out);
}